// Round 1
// baseline (577.736 us; speedup 1.0000x reference)
//
#include <hip/hip_runtime.h>
#include <cstdint>
#include <cstddef>

#define DI static __device__ __forceinline__

using half_t  = _Float16;
using half2_t = __attribute__((ext_vector_type(2))) _Float16;
using half8_t = __attribute__((ext_vector_type(8))) _Float16;
using f32x4_t = __attribute__((ext_vector_type(4))) float;

DI uint32_t pack2(float a, float b){ half2_t h; h[0]=(half_t)a; h[1]=(half_t)b; return __builtin_bit_cast(uint32_t,h); }
DI uint16_t f16b(float a){ return __builtin_bit_cast(uint16_t,(half_t)a); }
DI float fdot2(uint32_t w, uint32_t x, float acc){
  return __builtin_amdgcn_fdot2(__builtin_bit_cast(half2_t,w), __builtin_bit_cast(half2_t,x), acc, false);
}
DI float sigm(float x){ return __builtin_amdgcn_rcpf(1.f + __expf(-x)); }
DI float tanhf_(float x){ return 1.f - 2.f*__builtin_amdgcn_rcpf(__expf(2.f*x)+1.f); }

// problem sizes: B=32 S=64 NW=2048 T=198 L=50 WLEN=20 BERT=178 Hs=128 Hm=256 Din=306 O=32
#define SROW 308   // sentences_in row stride (306 used)

// prep job sizes
#define N0 32768   // word Whh f16x2 [kp64][j128][g4]
#define N1 12800   // word Wih f16x2 [kp25][j128][g4]
#define N2 8192    // Wl f16x2 [kp64][d128]
#define N3 512     // word bias sum [j128][g4]
#define N4 262144  // sent Whh B-frag layout [dir][ng1024][kp128]
#define N5 313344  // sent Wih f16x2 [dir][kp153][j256][g4]
#define N6 2048    // sent bias sum [dir][j256][g4]
#define N7 8192    // Wo f16x2 [kp256][o32]
#define N8 364544  // bert -> sent[:,128:306]
#define NTOT (N0+N1+N2+N3+N4+N5+N6+N7+N8)

__global__ void k_prep(const float* __restrict__ X,
                       const float* __restrict__ Wih_w, const float* __restrict__ Whh_w,
                       const float* __restrict__ bih_w, const float* __restrict__ bhh_w,
                       const float* __restrict__ Wl,
                       const float* __restrict__ Wih_f, const float* __restrict__ Whh_f,
                       const float* __restrict__ bih_f, const float* __restrict__ bhh_f,
                       const float* __restrict__ Wih_b, const float* __restrict__ Whh_b,
                       const float* __restrict__ bih_b, const float* __restrict__ bhh_b,
                       const float* __restrict__ Wo,
                       uint32_t* __restrict__ wWg, uint32_t* __restrict__ wWihw,
                       uint32_t* __restrict__ wWl, float* __restrict__ wbsw,
                       uint32_t* __restrict__ wWs, uint32_t* __restrict__ wWihs,
                       float* __restrict__ wbss, uint32_t* __restrict__ wWo,
                       float* __restrict__ sent)
{
  for (int i = blockIdx.x*blockDim.x + threadIdx.x; i < NTOT; i += gridDim.x*blockDim.x) {
    int id = i;
    if (id < N0) {                       // word Whh packed, transposed: [kp][j][g]
      int g = id & 3, j = (id>>2)&127, kp = id>>9;
      const float* s = Whh_w + (size_t)(g*128+j)*128 + 2*kp;
      wWg[id] = pack2(s[0], s[1]);
    } else if ((id -= N0) < N1) {        // word Wih packed [kp][j][g], 50 = 25 pairs
      int g = id & 3, j = (id>>2)&127, kp = id>>9;
      const float* s = Wih_w + (size_t)(g*128+j)*50 + 2*kp;
      wWihw[id] = pack2(s[0], s[1]);
    } else if ((id -= N1) < N2) {        // Wl packed [kp][d]
      int d = id & 127, kp = id>>7;
      const float* s = Wl + (size_t)d*128 + 2*kp;
      wWl[id] = pack2(s[0], s[1]);
    } else if ((id -= N2) < N3) {        // word bias sum [j][g]
      int g = id & 3, j = id>>2;
      wbsw[id] = bih_w[g*128+j] + bhh_w[g*128+j];
    } else if ((id -= N3) < N4) {        // sentence Whh in MFMA-B row layout [dir][ng][kp]
      int kp = id & 127, ng = (id>>7)&1023, dir = id>>17;
      int w = ng>>7, g = (ng>>5)&3, jl = ng&31;    // ng = wave*128 + g*32 + jl
      int row = g*256 + w*32 + jl;
      const float* s = (dir ? Whh_b : Whh_f) + (size_t)row*256 + 2*kp;
      wWs[id] = pack2(s[0], s[1]);
    } else if ((id -= N4) < N5) {        // sentence Wih packed [dir][kp][j][g], 306 = 153 pairs
      int dir = id >= 156672; int r = id - dir*156672;
      int g = r & 3, j = (r>>2)&255, kp = r>>10;
      const float* s = (dir ? Wih_b : Wih_f) + (size_t)(g*256+j)*306 + 2*kp;
      wWihs[id] = pack2(s[0], s[1]);
    } else if ((id -= N5) < N6) {        // sentence bias sums [dir][j][g]
      int g = id & 3, j = (id>>2)&255, dir = id>>10;
      int row = g*256+j;
      wbss[id] = dir ? (bih_b[row]+bhh_b[row]) : (bih_f[row]+bhh_f[row]);
    } else if ((id -= N6) < N7) {        // Wo packed [kp][o]
      int o = id & 31, kp = id>>5;
      const float* s = Wo + (size_t)o*512 + 2*kp;
      wWo[id] = pack2(s[0], s[1]);
    } else { id -= N7;                   // bert = Xw[:,20:198,0] -> sent[:,128:306]
      int wg = id / 178, ii = id % 178;
      sent[(size_t)wg*SROW + 128 + ii] = X[(size_t)wg*9900 + (20+ii)*50];
    }
  }
}

// ---- word LSTM: 8 words/block, Whh f16 LDS-stationary, xg computed on the fly.
// thread: j = tid&127 (hidden dim), ws4 = 4-word set. fdot2 inner loops.
__global__ __launch_bounds__(256) void k_word(
    const float* __restrict__ X, const float* __restrict__ h0w, const float* __restrict__ c0w,
    const uint32_t* __restrict__ Wg, const uint32_t* __restrict__ Wihp,
    const float* __restrict__ bsw, const uint32_t* __restrict__ Wl16,
    const float* __restrict__ bl, float* __restrict__ sent)
{
  extern __shared__ uint32_t u[];
  uint32_t* Wg_  = u;            // 32768 u32 : Whh f16x2 [kp64][j128][g4]
  uint32_t* let_ = u + 32768;    // 4000 u32  : letters f16x2 [t20][kp25][w8]
  uint32_t* h_   = u + 36768;    // 512 u32   : h f16x2 [kp64][w8]
  const int tid = threadIdx.x;
  const int wg0 = blockIdx.x * 8;
  for (int i = tid; i < 32768; i += 256) Wg_[i] = Wg[i];
  for (int i = tid; i < 4000; i += 256) {
    int w = i & 7, r = i >> 3; int kp = r % 25, t = r / 25;
    const float* xp = X + (size_t)(wg0+w)*9900 + t*50 + 2*kp;
    let_[i] = pack2(xp[0], xp[1]);
  }
  for (int i = tid; i < 512; i += 256) {
    int w = i & 7, kp = i >> 3;
    const float* hp = h0w + (size_t)(wg0+w)*128 + 2*kp;
    h_[i] = pack2(hp[0], hp[1]);
  }
  const int j = tid & 127, ws4 = (tid >> 7) * 4;
  float c[4];
  #pragma unroll
  for (int w = 0; w < 4; ++w) c[w] = c0w[(size_t)(wg0+ws4+w)*128 + j];
  const float4 bs = *(const float4*)(bsw + j*4);
  __syncthreads();

  for (int t = 0; t < 20; ++t) {
    float acc[4][4];
    #pragma unroll
    for (int w = 0; w < 4; ++w) { acc[w][0]=bs.x; acc[w][1]=bs.y; acc[w][2]=bs.z; acc[w][3]=bs.w; }
    for (int kp = 0; kp < 25; ++kp) {          // xg part: x_t . Wih
      uint4 wv = *(const uint4*)(Wihp + (kp*128 + j)*4);
      uint4 xv = *(const uint4*)(let_ + (t*25 + kp)*8 + ws4);
      uint32_t wa[4] = {wv.x,wv.y,wv.z,wv.w};
      uint32_t xa[4] = {xv.x,xv.y,xv.z,xv.w};
      #pragma unroll
      for (int w = 0; w < 4; ++w)
        #pragma unroll
        for (int g = 0; g < 4; ++g) acc[w][g] = fdot2(wa[g], xa[w], acc[w][g]);
    }
    for (int kp = 0; kp < 64; ++kp) {          // recurrent part: h . Whh
      uint4 wv = *(const uint4*)(Wg_ + (kp*128 + j)*4);
      uint4 hv = *(const uint4*)(h_ + kp*8 + ws4);
      uint32_t wa[4] = {wv.x,wv.y,wv.z,wv.w};
      uint32_t ha[4] = {hv.x,hv.y,hv.z,hv.w};
      #pragma unroll
      for (int w = 0; w < 4; ++w)
        #pragma unroll
        for (int g = 0; g < 4; ++g) acc[w][g] = fdot2(wa[g], ha[w], acc[w][g]);
    }
    __syncthreads();   // all h reads done
    uint16_t* h16 = (uint16_t*)h_;
    #pragma unroll
    for (int w = 0; w < 4; ++w) {              // gate order i,f,g,o
      float cc = sigm(acc[w][1])*c[w] + sigm(acc[w][0])*tanhf_(acc[w][2]);
      c[w] = cc;
      float hh = sigm(acc[w][3])*tanhf_(cc);
      h16[((j>>1)*8 + ws4 + w)*2 + (j&1)] = f16b(hh);
    }
    __syncthreads();
  }
  // word_rep = h_19 @ Wl^T + bl  -> sent[:,0:128]
  float r[4];
  #pragma unroll
  for (int w = 0; w < 4; ++w) r[w] = bl[j];
  for (int kp = 0; kp < 64; ++kp) {
    uint32_t wl = Wl16[kp*128 + j];
    uint4 hv = *(const uint4*)(h_ + kp*8 + ws4);
    uint32_t ha[4] = {hv.x,hv.y,hv.z,hv.w};
    #pragma unroll
    for (int w = 0; w < 4; ++w) r[w] = fdot2(wl, ha[w], r[w]);
  }
  #pragma unroll
  for (int w = 0; w < 4; ++w) sent[(size_t)(wg0+ws4+w)*SROW + j] = r[w];
}

// ---- sentence xg GEMM: xgp[dir][b*64+t][j][g] = sent[row] . Wih + bias (row reversed for bwd)
__global__ __launch_bounds__(256) void k_sxg(
    const float* __restrict__ sent, const uint32_t* __restrict__ Wihs,
    const float* __restrict__ bss, float* __restrict__ xgp)
{
  __shared__ uint32_t x16[153*8];
  const int tid = threadIdx.x;
  const int dir = blockIdx.x >> 8, rg = blockIdx.x & 255;
  for (int i = tid; i < 153*8; i += 256) {
    int r = i & 7, kp = i >> 3;
    int ot = rg*8 + r; int b = ot >> 6, tt = ot & 63;
    int si = dir ? (63 - tt) : tt;
    const float* s = sent + (size_t)(b*64 + si)*SROW + 2*kp;
    x16[kp*8 + r] = pack2(s[0], s[1]);
  }
  __syncthreads();
  const int j = tid;
  float acc[8][4];
  {
    const float4 b4 = *(const float4*)(bss + (dir*256 + j)*4);
    #pragma unroll
    for (int r = 0; r < 8; ++r) { acc[r][0]=b4.x; acc[r][1]=b4.y; acc[r][2]=b4.z; acc[r][3]=b4.w; }
  }
  for (int kp = 0; kp < 153; ++kp) {
    uint4 wv = *(const uint4*)(Wihs + ((size_t)(dir*153 + kp)*256 + j)*4);
    uint4 xa = *(const uint4*)(x16 + kp*8);
    uint4 xb = *(const uint4*)(x16 + kp*8 + 4);
    uint32_t wa[4] = {wv.x,wv.y,wv.z,wv.w};
    uint32_t xs[8] = {xa.x,xa.y,xa.z,xa.w,xb.x,xb.y,xb.z,xb.w};
    #pragma unroll
    for (int r = 0; r < 8; ++r)
      #pragma unroll
      for (int g = 0; g < 4; ++g) acc[r][g] = fdot2(wa[g], xs[r], acc[r][g]);
  }
  #pragma unroll
  for (int r = 0; r < 8; ++r) {
    int ot = rg*8 + r;
    float4 v = {acc[r][0], acc[r][1], acc[r][2], acc[r][3]};
    *(float4*)(xgp + ((size_t)(dir*2048 + ot)*256 + j)*4) = v;
  }
}

// ---- sentence recurrence: grid 4 = (dir, batch-half M=16). 8 waves, N=1024.
// Whh f16 stationary: 48 frags/lane in VGPR (Kt<6) + 16 frags in LDS (Kt 6,7).
// Gate-grouped N order: wave owns j in [32w,32w+32), all 4 gates -> update is lane-local.
__global__ __launch_bounds__(512, 2) void k_srec(
    const uint32_t* __restrict__ Ws, const float* __restrict__ h0f, const float* __restrict__ c0f,
    const float* __restrict__ h0b, const float* __restrict__ c0b,
    const float* __restrict__ xgp, uint16_t* __restrict__ outfb)
{
  extern __shared__ char smem[];               // [0,131072) B-frags, then h16[16][264]
  uint16_t* h16 = (uint16_t*)(smem + 131072);
  const int tid = threadIdx.x;
  const int wave = tid >> 6, lane = tid & 63;
  const int dir = blockIdx.x >> 1, m0 = (blockIdx.x & 1) * 16;
  const int l15 = lane & 15, l4 = lane >> 4;

  uint4 Breg[8][6];
  #pragma unroll
  for (int Nt = 0; Nt < 8; ++Nt) {
    #pragma unroll
    for (int Kt = 0; Kt < 8; ++Kt) {
      int ng = wave*128 + Nt*16 + l15;
      int kq = Kt*16 + l4*4;                   // u32 index = k0/2
      uint4 v = *(const uint4*)(Ws + (size_t)(dir*1024 + ng)*128 + kq);
      if (Kt < 6) Breg[Nt][Kt] = v;
      else *(uint4*)(smem + (((wave*16 + Nt*2 + (Kt-6))*64 + lane)*16)) = v;
    }
  }
  {
    const float* h0 = dir ? h0b : h0f;
    for (int i = tid; i < 16*256; i += 512) {
      int m = i >> 8, k = i & 255;
      h16[m*264 + k] = f16b(h0[(size_t)(m0+m)*256 + k]);
    }
  }
  float cr[2][4];
  {
    const float* c0 = dir ? c0b : c0f;
    #pragma unroll
    for (int jh = 0; jh < 2; ++jh)
      #pragma unroll
      for (int r = 0; r < 4; ++r) {
        int m = l4*4 + r, jj = wave*32 + jh*16 + l15;
        cr[jh][r] = c0[(size_t)(m0+m)*256 + jj];
      }
  }
  __syncthreads();

  for (int t = 0; t < 64; ++t) {
    f32x4_t acc[8];
    #pragma unroll
    for (int n = 0; n < 8; ++n) acc[n] = (f32x4_t){0.f,0.f,0.f,0.f};
    #pragma unroll
    for (int Kt = 0; Kt < 8; ++Kt) {
      uint4 av = *(const uint4*)(h16 + l15*264 + Kt*32 + l4*8);   // A frag: row=l15, k=Kt*32+l4*8
      half8_t a = __builtin_bit_cast(half8_t, av);
      #pragma unroll
      for (int Nt = 0; Nt < 8; ++Nt) {
        uint4 bv = (Kt < 6) ? Breg[Nt][Kt]
                 : *(const uint4*)(smem + (((wave*16 + Nt*2 + (Kt-6))*64 + lane)*16));
        acc[Nt] = __builtin_amdgcn_mfma_f32_16x16x32_f16(a, __builtin_bit_cast(half8_t, bv), acc[Nt], 0,0,0);
      }
    }
    __syncthreads();   // all reads of h16 complete
    const int s = dir ? (63 - t) : t;
    #pragma unroll
    for (int jh = 0; jh < 2; ++jh) {
      #pragma unroll
      for (int r = 0; r < 4; ++r) {
        int m = l4*4 + r, jj = wave*32 + jh*16 + l15;
        float gi = acc[0+jh][r], gf = acc[2+jh][r], gg = acc[4+jh][r], go = acc[6+jh][r];
        const float4 xg = *(const float4*)(xgp + ((size_t)(dir*2048 + (m0+m)*64 + t)*256 + jj)*4);
        gi += xg.x; gf += xg.y; gg += xg.z; go += xg.w;
        float cc = sigm(gf)*cr[jh][r] + sigm(gi)*tanhf_(gg);
        cr[jh][r] = cc;
        float hh = sigm(go)*tanhf_(cc);
        uint16_t hb = f16b(hh);
        h16[m*264 + jj] = hb;
        outfb[((size_t)(m0+m)*64 + s)*512 + dir*256 + jj] = hb;
      }
    }
    __syncthreads();
  }
}

// ---- tags + softmax
__global__ __launch_bounds__(256) void k_tags(
    const uint16_t* __restrict__ outfb, const uint32_t* __restrict__ Wo16,
    const float* __restrict__ bo, float* __restrict__ out)
{
  __shared__ uint32_t xr[8*256];
  const int tid = threadIdx.x;
  const int w0 = blockIdx.x * 8;
  const uint32_t* src = (const uint32_t*)outfb;
  for (int i = tid; i < 2048; i += 256) {
    int w = i >> 8, kp = i & 255;
    xr[i] = src[(size_t)(w0+w)*256 + kp];
  }
  __syncthreads();
  const int o = tid & 31, w = tid >> 5;
  float a = bo[o];
  for (int kp = 0; kp < 256; ++kp)
    a = fdot2(Wo16[kp*32 + o], xr[w*256 + kp], a);
  float mx = a;
  #pragma unroll
  for (int off = 16; off; off >>= 1) mx = fmaxf(mx, __shfl_xor(mx, off, 32));
  float e = __expf(a - mx);
  float ssum = e;
  #pragma unroll
  for (int off = 16; off; off >>= 1) ssum += __shfl_xor(ssum, off, 32);
  out[(size_t)(w0+w)*32 + o] = e * __builtin_amdgcn_rcpf(ssum);
}

extern "C" void kernel_launch(void* const* d_in, const int* in_sizes, int n_in,
                              void* d_out, int out_size, void* d_ws, size_t ws_size,
                              hipStream_t stream) {
  const float* X     = (const float*)d_in[0];
  const float* h0w   = (const float*)d_in[1];
  const float* c0w   = (const float*)d_in[2];
  const float* h0f   = (const float*)d_in[3];
  const float* c0f   = (const float*)d_in[4];
  const float* h0b   = (const float*)d_in[5];
  const float* c0b   = (const float*)d_in[6];
  const float* Wih_w = (const float*)d_in[7];
  const float* Whh_w = (const float*)d_in[8];
  const float* bih_w = (const float*)d_in[9];
  const float* bhh_w = (const float*)d_in[10];
  const float* Wl    = (const float*)d_in[11];
  const float* bl    = (const float*)d_in[12];
  const float* Wih_f = (const float*)d_in[13];
  const float* Whh_f = (const float*)d_in[14];
  const float* bih_f = (const float*)d_in[15];
  const float* bhh_f = (const float*)d_in[16];
  const float* Wih_b = (const float*)d_in[17];
  const float* Whh_b = (const float*)d_in[18];
  const float* bih_b = (const float*)d_in[19];
  const float* bhh_b = (const float*)d_in[20];
  const float* Wo    = (const float*)d_in[21];
  const float* bo    = (const float*)d_in[22];

  char* ws = (char*)d_ws;
  uint32_t* wWg   = (uint32_t*)(ws + 0);
  uint32_t* wWihw = (uint32_t*)(ws + 131072);
  uint32_t* wWl   = (uint32_t*)(ws + 182272);
  float*    wbsw  = (float*)   (ws + 215040);
  uint32_t* wWs   = (uint32_t*)(ws + 217088);
  uint32_t* wWihs = (uint32_t*)(ws + 1265664);
  float*    wbss  = (float*)   (ws + 2519040);
  uint32_t* wWo   = (uint32_t*)(ws + 2527232);
  float*    sent  = (float*)   (ws + 2560000);
  float*    xgp   = (float*)   (ws + 5083136);
  uint16_t* outfb = (uint16_t*)(ws + 21860352);   // total ~24 MB

  hipFuncSetAttribute((const void*)k_word, hipFuncAttributeMaxDynamicSharedMemorySize, 149120);
  hipFuncSetAttribute((const void*)k_srec, hipFuncAttributeMaxDynamicSharedMemorySize, 139520);

  k_prep<<<2048, 256, 0, stream>>>(X, Wih_w, Whh_w, bih_w, bhh_w, Wl, Wih_f, Whh_f, bih_f, bhh_f,
                                   Wih_b, Whh_b, bih_b, bhh_b, Wo,
                                   wWg, wWihw, wWl, wbsw, wWs, wWihs, wbss, wWo, sent);
  k_word<<<256, 256, 149120, stream>>>(X, h0w, c0w, wWg, wWihw, wbsw, wWl, bl, sent);
  k_sxg<<<512, 256, 0, stream>>>(sent, wWihs, wbss, xgp);
  k_srec<<<4, 512, 139520, stream>>>(wWs, h0f, c0f, h0b, c0b, xgp, outfb);
  k_tags<<<256, 256, 0, stream>>>(outfb, wWo, bo, (float*)d_out);
}

// Round 2
// 407.095 us; speedup vs baseline: 1.4192x; 1.4192x over previous
//
#include <hip/hip_runtime.h>
#include <cstdint>
#include <cstddef>

#define DI static __device__ __forceinline__

using half_t  = _Float16;
using half2_t = __attribute__((ext_vector_type(2))) _Float16;
using half8_t = __attribute__((ext_vector_type(8))) _Float16;
using f32x4_t = __attribute__((ext_vector_type(4))) float;

DI uint32_t pack2(float a, float b){ half2_t h; h[0]=(half_t)a; h[1]=(half_t)b; return __builtin_bit_cast(uint32_t,h); }
DI uint16_t f16b(float a){ return __builtin_bit_cast(uint16_t,(half_t)a); }
DI float lo16(uint32_t u){ half2_t h=__builtin_bit_cast(half2_t,u); return (float)h[0]; }
DI float hi16(uint32_t u){ half2_t h=__builtin_bit_cast(half2_t,u); return (float)h[1]; }
DI float fdot2(uint32_t w, uint32_t x, float acc){
  return __builtin_amdgcn_fdot2(__builtin_bit_cast(half2_t,w), __builtin_bit_cast(half2_t,x), acc, false);
}
DI float sigm(float x){ return __builtin_amdgcn_rcpf(1.f + __expf(-x)); }
DI float tanhf_(float x){ return 1.f - 2.f*__builtin_amdgcn_rcpf(__expf(2.f*x)+1.f); }

// problem sizes: B=32 S=64 NW=2048 T=198 L=50 WLEN=20 BERT=178 Hs=128 Hm=256 Din=306 O=32
#define SROW 308   // sentences_in row stride (306 used)

// prep job sizes
#define N0 32768   // word Whh f16x2 [kp64][j128][g4]
#define N1 12800   // word Wih f16x2 [kp25][j128][g4]
#define N2 8192    // Wl f16x2 [kp64][d128]
#define N3 512     // word bias sum [j128][g4]
#define N4 262144  // sent Whh B-frag layout [dir][ng1024][kp128]
#define N5 313344  // sent Wih f16x2 [dir][kp153][j256][g4]
#define N6 2048    // sent bias sum [dir][j256][g4]
#define N7 8192    // Wo f16x2 [kp256][o32]
#define N8 364544  // bert -> sent[:,128:306]
#define NTOT (N0+N1+N2+N3+N4+N5+N6+N7+N8)

__global__ void k_prep(const float* __restrict__ X,
                       const float* __restrict__ Wih_w, const float* __restrict__ Whh_w,
                       const float* __restrict__ bih_w, const float* __restrict__ bhh_w,
                       const float* __restrict__ Wl,
                       const float* __restrict__ Wih_f, const float* __restrict__ Whh_f,
                       const float* __restrict__ bih_f, const float* __restrict__ bhh_f,
                       const float* __restrict__ Wih_b, const float* __restrict__ Whh_b,
                       const float* __restrict__ bih_b, const float* __restrict__ bhh_b,
                       const float* __restrict__ Wo,
                       uint32_t* __restrict__ wWg, uint32_t* __restrict__ wWihw,
                       uint32_t* __restrict__ wWl, float* __restrict__ wbsw,
                       uint32_t* __restrict__ wWs, uint32_t* __restrict__ wWihs,
                       float* __restrict__ wbss, uint32_t* __restrict__ wWo,
                       float* __restrict__ sent)
{
  for (int i = blockIdx.x*blockDim.x + threadIdx.x; i < NTOT; i += gridDim.x*blockDim.x) {
    int id = i;
    if (id < N0) {                       // word Whh packed, transposed: [kp][j][g]
      int g = id & 3, j = (id>>2)&127, kp = id>>9;
      const float* s = Whh_w + (size_t)(g*128+j)*128 + 2*kp;
      wWg[id] = pack2(s[0], s[1]);
    } else if ((id -= N0) < N1) {        // word Wih packed [kp][j][g], 50 = 25 pairs
      int g = id & 3, j = (id>>2)&127, kp = id>>9;
      const float* s = Wih_w + (size_t)(g*128+j)*50 + 2*kp;
      wWihw[id] = pack2(s[0], s[1]);
    } else if ((id -= N1) < N2) {        // Wl packed [kp][d]
      int d = id & 127, kp = id>>7;
      const float* s = Wl + (size_t)d*128 + 2*kp;
      wWl[id] = pack2(s[0], s[1]);
    } else if ((id -= N2) < N3) {        // word bias sum [j][g]
      int g = id & 3, j = id>>2;
      wbsw[id] = bih_w[g*128+j] + bhh_w[g*128+j];
    } else if ((id -= N3) < N4) {        // sentence Whh in MFMA-B row layout [dir][ng][kp]
      int kp = id & 127, ng = (id>>7)&1023, dir = id>>17;
      int w = ng>>7, g = (ng>>5)&3, jl = ng&31;    // ng = wave*128 + g*32 + jl
      int row = g*256 + w*32 + jl;
      const float* s = (dir ? Whh_b : Whh_f) + (size_t)row*256 + 2*kp;
      wWs[id] = pack2(s[0], s[1]);
    } else if ((id -= N4) < N5) {        // sentence Wih packed [dir][kp][j][g], 306 = 153 pairs
      int dir = id >= 156672; int r = id - dir*156672;
      int g = r & 3, j = (r>>2)&255, kp = r>>10;
      const float* s = (dir ? Wih_b : Wih_f) + (size_t)(g*256+j)*306 + 2*kp;
      wWihs[id] = pack2(s[0], s[1]);
    } else if ((id -= N5) < N6) {        // sentence bias sums [dir][j][g]
      int g = id & 3, j = (id>>2)&255, dir = id>>10;
      int row = g*256+j;
      wbss[id] = dir ? (bih_b[row]+bhh_b[row]) : (bih_f[row]+bhh_f[row]);
    } else if ((id -= N6) < N7) {        // Wo packed [kp][o]
      int o = id & 31, kp = id>>5;
      const float* s = Wo + (size_t)o*512 + 2*kp;
      wWo[id] = pack2(s[0], s[1]);
    } else { id -= N7;                   // bert = Xw[:,20:198,0] -> sent[:,128:306]
      int wg = id / 178, ii = id % 178;
      sent[(size_t)wg*SROW + 128 + ii] = X[(size_t)wg*9900 + (20+ii)*50];
    }
  }
}

// ---- word LSTM: 8 words/block, Whh f16 LDS-stationary, xg computed on the fly.
__global__ __launch_bounds__(256) void k_word(
    const float* __restrict__ X, const float* __restrict__ h0w, const float* __restrict__ c0w,
    const uint32_t* __restrict__ Wg, const uint32_t* __restrict__ Wihp,
    const float* __restrict__ bsw, const uint32_t* __restrict__ Wl16,
    const float* __restrict__ bl, float* __restrict__ sent)
{
  extern __shared__ uint32_t u[];
  uint32_t* Wg_  = u;            // 32768 u32 : Whh f16x2 [kp64][j128][g4]
  uint32_t* let_ = u + 32768;    // 4000 u32  : letters f16x2 [t20][kp25][w8]
  uint32_t* h_   = u + 36768;    // 512 u32   : h f16x2 [kp64][w8]
  const int tid = threadIdx.x;
  const int wg0 = blockIdx.x * 8;
  for (int i = tid; i < 32768; i += 256) Wg_[i] = Wg[i];
  for (int i = tid; i < 4000; i += 256) {
    int w = i & 7, r = i >> 3; int kp = r % 25, t = r / 25;
    const float* xp = X + (size_t)(wg0+w)*9900 + t*50 + 2*kp;
    let_[i] = pack2(xp[0], xp[1]);
  }
  for (int i = tid; i < 512; i += 256) {
    int w = i & 7, kp = i >> 3;
    const float* hp = h0w + (size_t)(wg0+w)*128 + 2*kp;
    h_[i] = pack2(hp[0], hp[1]);
  }
  const int j = tid & 127, ws4 = (tid >> 7) * 4;
  float c[4];
  #pragma unroll
  for (int w = 0; w < 4; ++w) c[w] = c0w[(size_t)(wg0+ws4+w)*128 + j];
  const float4 bs = *(const float4*)(bsw + j*4);
  __syncthreads();

  for (int t = 0; t < 20; ++t) {
    float acc[4][4];
    #pragma unroll
    for (int w = 0; w < 4; ++w) { acc[w][0]=bs.x; acc[w][1]=bs.y; acc[w][2]=bs.z; acc[w][3]=bs.w; }
    for (int kp = 0; kp < 25; ++kp) {          // xg part: x_t . Wih
      uint4 wv = *(const uint4*)(Wihp + (kp*128 + j)*4);
      uint4 xv = *(const uint4*)(let_ + (t*25 + kp)*8 + ws4);
      uint32_t wa[4] = {wv.x,wv.y,wv.z,wv.w};
      uint32_t xa[4] = {xv.x,xv.y,xv.z,xv.w};
      #pragma unroll
      for (int w = 0; w < 4; ++w)
        #pragma unroll
        for (int g = 0; g < 4; ++g) acc[w][g] = fdot2(wa[g], xa[w], acc[w][g]);
    }
    for (int kp = 0; kp < 64; ++kp) {          // recurrent part: h . Whh
      uint4 wv = *(const uint4*)(Wg_ + (kp*128 + j)*4);
      uint4 hv = *(const uint4*)(h_ + kp*8 + ws4);
      uint32_t wa[4] = {wv.x,wv.y,wv.z,wv.w};
      uint32_t ha[4] = {hv.x,hv.y,hv.z,hv.w};
      #pragma unroll
      for (int w = 0; w < 4; ++w)
        #pragma unroll
        for (int g = 0; g < 4; ++g) acc[w][g] = fdot2(wa[g], ha[w], acc[w][g]);
    }
    __syncthreads();   // all h reads done
    uint16_t* h16 = (uint16_t*)h_;
    #pragma unroll
    for (int w = 0; w < 4; ++w) {              // gate order i,f,g,o
      float cc = sigm(acc[w][1])*c[w] + sigm(acc[w][0])*tanhf_(acc[w][2]);
      c[w] = cc;
      float hh = sigm(acc[w][3])*tanhf_(cc);
      h16[((j>>1)*8 + ws4 + w)*2 + (j&1)] = f16b(hh);
    }
    __syncthreads();
  }
  // word_rep = h_19 @ Wl^T + bl  -> sent[:,0:128]
  float r[4];
  #pragma unroll
  for (int w = 0; w < 4; ++w) r[w] = bl[j];
  for (int kp = 0; kp < 64; ++kp) {
    uint32_t wl = Wl16[kp*128 + j];
    uint4 hv = *(const uint4*)(h_ + kp*8 + ws4);
    uint32_t ha[4] = {hv.x,hv.y,hv.z,hv.w};
    #pragma unroll
    for (int w = 0; w < 4; ++w) r[w] = fdot2(wl, ha[w], r[w]);
  }
  #pragma unroll
  for (int w = 0; w < 4; ++w) sent[(size_t)(wg0+ws4+w)*SROW + j] = r[w];
}

// ---- sentence xg GEMM: xgh[dir][m*64+t][j] = 4xf16 {i,f,g,o} preacts (row reversed for bwd)
__global__ __launch_bounds__(256) void k_sxg(
    const float* __restrict__ sent, const uint32_t* __restrict__ Wihs,
    const float* __restrict__ bss, uint2* __restrict__ xgh)
{
  __shared__ uint32_t x16[153*8];
  const int tid = threadIdx.x;
  const int dir = blockIdx.x >> 8, rg = blockIdx.x & 255;
  for (int i = tid; i < 153*8; i += 256) {
    int r = i & 7, kp = i >> 3;
    int ot = rg*8 + r; int b = ot >> 6, tt = ot & 63;
    int si = dir ? (63 - tt) : tt;
    const float* s = sent + (size_t)(b*64 + si)*SROW + 2*kp;
    x16[kp*8 + r] = pack2(s[0], s[1]);
  }
  __syncthreads();
  const int j = tid;
  float acc[8][4];
  {
    const float4 b4 = *(const float4*)(bss + (dir*256 + j)*4);
    #pragma unroll
    for (int r = 0; r < 8; ++r) { acc[r][0]=b4.x; acc[r][1]=b4.y; acc[r][2]=b4.z; acc[r][3]=b4.w; }
  }
  for (int kp = 0; kp < 153; ++kp) {
    uint4 wv = *(const uint4*)(Wihs + ((size_t)(dir*153 + kp)*256 + j)*4);
    uint4 xa = *(const uint4*)(x16 + kp*8);
    uint4 xb = *(const uint4*)(x16 + kp*8 + 4);
    uint32_t wa[4] = {wv.x,wv.y,wv.z,wv.w};
    uint32_t xs[8] = {xa.x,xa.y,xa.z,xa.w,xb.x,xb.y,xb.z,xb.w};
    #pragma unroll
    for (int r = 0; r < 8; ++r)
      #pragma unroll
      for (int g = 0; g < 4; ++g) acc[r][g] = fdot2(wa[g], xs[r], acc[r][g]);
  }
  #pragma unroll
  for (int r = 0; r < 8; ++r) {
    int ot = rg*8 + r;
    uint2 v; v.x = pack2(acc[r][0], acc[r][1]); v.y = pack2(acc[r][2], acc[r][3]);
    xgh[(size_t)(dir*2048 + ot)*256 + j] = v;
  }
}

// ---- sentence recurrence: grid 4 = (dir, batch-half M=16). 8 waves, N=1024.
// Spill-free budget: Breg[8][6]=192 VGPR, Kt 6,7 in LDS (128 KB), acc jh-split (16),
// xg f16 prefetch (16), h16 double-buffered, one raw-asm barrier per step.
__global__ __launch_bounds__(512, 2) void k_srec(
    const uint32_t* __restrict__ Ws, const float* __restrict__ h0f, const float* __restrict__ c0f,
    const float* __restrict__ h0b, const float* __restrict__ c0b,
    const uint2* __restrict__ xgh, uint16_t* __restrict__ outfb)
{
  extern __shared__ char smem[];               // [0,131072) B-frags, then h16[2][16][264]
  uint16_t* h16 = (uint16_t*)(smem + 131072);
  const int tid = threadIdx.x;
  const int wave = tid >> 6, lane = tid & 63;
  const int dir = blockIdx.x >> 1, m0 = (blockIdx.x & 1) * 16;
  const int l15 = lane & 15, l4 = lane >> 4;

  uint4 Breg[8][6];
  #pragma unroll
  for (int Nt = 0; Nt < 8; ++Nt) {
    #pragma unroll
    for (int Kt = 0; Kt < 8; ++Kt) {
      int ng = wave*128 + Nt*16 + l15;
      int kq = Kt*16 + l4*4;                   // u32 index = k0/2
      uint4 v = *(const uint4*)(Ws + (size_t)(dir*1024 + ng)*128 + kq);
      if (Kt < 6) Breg[Nt][Kt] = v;
      else *(uint4*)(smem + (((wave*16 + Nt*2 + (Kt-6))*64 + lane)*16)) = v;
    }
  }
  {
    const float* h0 = dir ? h0b : h0f;
    for (int i = tid; i < 16*256; i += 512) {
      int m = i >> 8, k = i & 255;
      h16[m*264 + k] = f16b(h0[(size_t)(m0+m)*256 + k]);
    }
  }
  float cr[2][4];
  {
    const float* c0 = dir ? c0b : c0f;
    #pragma unroll
    for (int jh = 0; jh < 2; ++jh)
      #pragma unroll
      for (int r = 0; r < 4; ++r) {
        int m = l4*4 + r, jj = wave*32 + jh*16 + l15;
        cr[jh][r] = c0[(size_t)(m0+m)*256 + jj];
      }
  }
  __syncthreads();

  // running pointers (per-lane)
  const uint2* xp = xgh + (size_t)(dir*2048 + (m0 + l4*4)*64)*256 + wave*32 + l15;
  const int s0 = dir ? 63 : 0, dstep = dir ? -1 : 1;
  uint16_t* op = outfb + ((size_t)(m0 + l4*4)*64 + s0)*512 + dir*256 + wave*32 + l15;

  for (int t = 0; t < 64; ++t) {
    const uint16_t* hc = h16 + (t & 1) * 4224;       // 16*264
    uint16_t* hn = h16 + ((t & 1) ^ 1) * 4224;
    // prefetch this step's xg (f16x4 per output) — latency hides under MFMA passes
    uint2 xg[2][4];
    #pragma unroll
    for (int jh = 0; jh < 2; ++jh)
      #pragma unroll
      for (int r = 0; r < 4; ++r)
        xg[jh][r] = xp[(size_t)r*16384 + jh*16];

    #pragma unroll
    for (int jh = 0; jh < 2; ++jh) {                 // gate-half pass: Nt = g*2+jh
      f32x4_t acc[4];
      #pragma unroll
      for (int g = 0; g < 4; ++g) acc[g] = (f32x4_t){0.f,0.f,0.f,0.f};
      #pragma unroll
      for (int Kt = 0; Kt < 8; ++Kt) {
        uint4 av = *(const uint4*)(hc + l15*264 + Kt*32 + l4*8);
        half8_t a = __builtin_bit_cast(half8_t, av);
        #pragma unroll
        for (int g = 0; g < 4; ++g) {
          const int Nt = g*2 + jh;
          uint4 bv = (Kt < 6) ? Breg[Nt][Kt]
                   : *(const uint4*)(smem + (((wave*16 + Nt*2 + (Kt-6))*64 + lane)*16));
          acc[g] = __builtin_amdgcn_mfma_f32_16x16x32_f16(a, __builtin_bit_cast(half8_t, bv), acc[g], 0,0,0);
        }
      }
      #pragma unroll
      for (int r = 0; r < 4; ++r) {
        int m = l4*4 + r, jj = wave*32 + jh*16 + l15;
        float gi = acc[0][r] + lo16(xg[jh][r].x);
        float gf = acc[1][r] + hi16(xg[jh][r].x);
        float gg = acc[2][r] + lo16(xg[jh][r].y);
        float go = acc[3][r] + hi16(xg[jh][r].y);
        // fused-denominator LSTM update: 5 exp + 2 rcp
        float ef = __expf(-gf), ei = __expf(-gi), eg = __expf(-2.f*gg);
        float pef = 1.f + ef, pei = 1.f + ei, peg = 1.f + eg;
        float num = cr[jh][r]*pei*peg + (1.f - eg)*pef;
        float cc  = num * __builtin_amdgcn_rcpf(pef*pei*peg);
        cr[jh][r] = cc;
        float ec = __expf(-2.f*cc), eo = __expf(-go);
        float hh = (1.f - ec) * __builtin_amdgcn_rcpf((1.f + ec)*(1.f + eo));
        uint16_t hb = f16b(hh);
        hn[m*264 + jj] = hb;
        op[(size_t)r*32768 + jh*16] = hb;
      }
    }
    xp += 256;
    op += dstep * 512;
    // h16 is double-buffered and outfb/xg are per-wave global ops:
    // only LDS writes must be visible -> lgkm drain + raw barrier (no vmcnt drain)
    asm volatile("s_waitcnt lgkmcnt(0)\ns_barrier" ::: "memory");
    __builtin_amdgcn_sched_barrier(0);
  }
}

// ---- tags + softmax
__global__ __launch_bounds__(256) void k_tags(
    const uint16_t* __restrict__ outfb, const uint32_t* __restrict__ Wo16,
    const float* __restrict__ bo, float* __restrict__ out)
{
  __shared__ uint32_t xr[8*256];
  const int tid = threadIdx.x;
  const int w0 = blockIdx.x * 8;
  const uint32_t* src = (const uint32_t*)outfb;
  for (int i = tid; i < 2048; i += 256) {
    int w = i >> 8, kp = i & 255;
    xr[i] = src[(size_t)(w0+w)*256 + kp];
  }
  __syncthreads();
  const int o = tid & 31, w = tid >> 5;
  float a = bo[o];
  for (int kp = 0; kp < 256; ++kp)
    a = fdot2(Wo16[kp*32 + o], xr[w*256 + kp], a);
  float mx = a;
  #pragma unroll
  for (int off = 16; off; off >>= 1) mx = fmaxf(mx, __shfl_xor(mx, off, 32));
  float e = __expf(a - mx);
  float ssum = e;
  #pragma unroll
  for (int off = 16; off; off >>= 1) ssum += __shfl_xor(ssum, off, 32);
  out[(size_t)(w0+w)*32 + o] = e * __builtin_amdgcn_rcpf(ssum);
}

extern "C" void kernel_launch(void* const* d_in, const int* in_sizes, int n_in,
                              void* d_out, int out_size, void* d_ws, size_t ws_size,
                              hipStream_t stream) {
  const float* X     = (const float*)d_in[0];
  const float* h0w   = (const float*)d_in[1];
  const float* c0w   = (const float*)d_in[2];
  const float* h0f   = (const float*)d_in[3];
  const float* c0f   = (const float*)d_in[4];
  const float* h0b   = (const float*)d_in[5];
  const float* c0b   = (const float*)d_in[6];
  const float* Wih_w = (const float*)d_in[7];
  const float* Whh_w = (const float*)d_in[8];
  const float* bih_w = (const float*)d_in[9];
  const float* bhh_w = (const float*)d_in[10];
  const float* Wl    = (const float*)d_in[11];
  const float* bl    = (const float*)d_in[12];
  const float* Wih_f = (const float*)d_in[13];
  const float* Whh_f = (const float*)d_in[14];
  const float* bih_f = (const float*)d_in[15];
  const float* bhh_f = (const float*)d_in[16];
  const float* Wih_b = (const float*)d_in[17];
  const float* Whh_b = (const float*)d_in[18];
  const float* bih_b = (const float*)d_in[19];
  const float* bhh_b = (const float*)d_in[20];
  const float* Wo    = (const float*)d_in[21];
  const float* bo    = (const float*)d_in[22];

  char* ws = (char*)d_ws;
  uint32_t* wWg   = (uint32_t*)(ws + 0);
  uint32_t* wWihw = (uint32_t*)(ws + 131072);
  uint32_t* wWl   = (uint32_t*)(ws + 182272);
  float*    wbsw  = (float*)   (ws + 215040);
  uint32_t* wWs   = (uint32_t*)(ws + 217088);
  uint32_t* wWihs = (uint32_t*)(ws + 1265664);
  float*    wbss  = (float*)   (ws + 2519040);
  uint32_t* wWo   = (uint32_t*)(ws + 2527232);
  float*    sent  = (float*)   (ws + 2560000);
  uint2*    xgh   = (uint2*)   (ws + 5083136);    // [2][2048][256] uint2 = 8.4 MB
  uint16_t* outfb = (uint16_t*)(ws + 21860352);

  hipFuncSetAttribute((const void*)k_word, hipFuncAttributeMaxDynamicSharedMemorySize, 149120);
  hipFuncSetAttribute((const void*)k_srec, hipFuncAttributeMaxDynamicSharedMemorySize, 147968);

  k_prep<<<2048, 256, 0, stream>>>(X, Wih_w, Whh_w, bih_w, bhh_w, Wl, Wih_f, Whh_f, bih_f, bhh_f,
                                   Wih_b, Whh_b, bih_b, bhh_b, Wo,
                                   wWg, wWihw, wWl, wbsw, wWs, wWihs, wbss, wWo, sent);
  k_word<<<256, 256, 149120, stream>>>(X, h0w, c0w, wWg, wWihw, wbsw, wWl, bl, sent);
  k_sxg<<<512, 256, 0, stream>>>(sent, wWihs, wbss, xgh);
  k_srec<<<4, 512, 147968, stream>>>(wWs, h0f, c0f, h0b, c0b, xgh, outfb);
  k_tags<<<256, 256, 0, stream>>>(outfb, wWo, bo, (float*)d_out);
}

// Round 3
// 336.030 us; speedup vs baseline: 1.7193x; 1.2115x over previous
//
#include <hip/hip_runtime.h>
#include <cstdint>
#include <cstddef>

#define DI static __device__ __forceinline__

using half_t  = _Float16;
using half2_t = __attribute__((ext_vector_type(2))) _Float16;
using half8_t = __attribute__((ext_vector_type(8))) _Float16;
using f32x4_t = __attribute__((ext_vector_type(4))) float;

DI uint32_t pack2(float a, float b){ half2_t h; h[0]=(half_t)a; h[1]=(half_t)b; return __builtin_bit_cast(uint32_t,h); }
DI uint16_t f16b(float a){ return __builtin_bit_cast(uint16_t,(half_t)a); }
DI float lo16(uint32_t u){ half2_t h=__builtin_bit_cast(half2_t,u); return (float)h[0]; }
DI float hi16(uint32_t u){ half2_t h=__builtin_bit_cast(half2_t,u); return (float)h[1]; }
DI float fdot2(uint32_t w, uint32_t x, float acc){
  return __builtin_amdgcn_fdot2(__builtin_bit_cast(half2_t,w), __builtin_bit_cast(half2_t,x), acc, false);
}
DI float sigm(float x){ return __builtin_amdgcn_rcpf(1.f + __expf(-x)); }
DI float tanhf_(float x){ return 1.f - 2.f*__builtin_amdgcn_rcpf(__expf(2.f*x)+1.f); }

// problem sizes: B=32 S=64 NW=2048 T=198 L=50 WLEN=20 BERT=178 Hs=128 Hm=256 Din=306 O=32
#define SROW 308   // sentences_in row stride (306 used)

// prep job sizes
#define N0 32768   // word Whh MFMA-B frags [ng512][kp64]
#define N1 16384   // word Wih MFMA-B frags [ng512][kp32] (k=50 zero-padded to 64)
#define N2 8192    // Wl MFMA-B frags [d128][kp64]
#define N3 512     // word bias sum [j128][g4]
#define N4 262144  // sent Whh B-frag layout [dir][ng1024][kp128]
#define N5 313344  // sent Wih f16x2 [dir][kp153][j256][g4]
#define N6 2048    // sent bias sum [dir][j256][g4]
#define N7 8192    // Wo f16x2 [kp256][o32]
#define N8 364544  // bert -> sent[:,128:306]
#define NTOT (N0+N1+N2+N3+N4+N5+N6+N7+N8)

__global__ void k_prep(const float* __restrict__ X,
                       const float* __restrict__ Wih_w, const float* __restrict__ Whh_w,
                       const float* __restrict__ bih_w, const float* __restrict__ bhh_w,
                       const float* __restrict__ Wl,
                       const float* __restrict__ Wih_f, const float* __restrict__ Whh_f,
                       const float* __restrict__ bih_f, const float* __restrict__ bhh_f,
                       const float* __restrict__ Wih_b, const float* __restrict__ Whh_b,
                       const float* __restrict__ bih_b, const float* __restrict__ bhh_b,
                       const float* __restrict__ Wo,
                       uint32_t* __restrict__ wWsw, uint32_t* __restrict__ wWxw,
                       uint32_t* __restrict__ wWlf, float* __restrict__ wbsw,
                       uint32_t* __restrict__ wWs, uint32_t* __restrict__ wWihs,
                       float* __restrict__ wbss, uint32_t* __restrict__ wWo,
                       float* __restrict__ sent)
{
  for (int i = blockIdx.x*blockDim.x + threadIdx.x; i < NTOT; i += gridDim.x*blockDim.x) {
    int id = i;
    if (id < N0) {                       // word Whh B-frags: ng = w*64+g*16+jl -> row g*128+w*16+jl
      int kp = id & 63, ng = id >> 6;
      int w = ng>>6, g = (ng>>4)&3, jl = ng&15;
      const float* s = Whh_w + (size_t)(g*128 + w*16 + jl)*128 + 2*kp;
      wWsw[id] = pack2(s[0], s[1]);
    } else if ((id -= N0) < N1) {        // word Wih B-frags, k padded 50->64
      int kp = id & 31, ng = id >> 5;
      int w = ng>>6, g = (ng>>4)&3, jl = ng&15;
      if (kp < 25) {
        const float* s = Wih_w + (size_t)(g*128 + w*16 + jl)*50 + 2*kp;
        wWxw[id] = pack2(s[0], s[1]);
      } else wWxw[id] = 0u;
    } else if ((id -= N1) < N2) {        // Wl B-frags [d][kp]
      int kp = id & 63, d = id >> 6;
      const float* s = Wl + (size_t)d*128 + 2*kp;
      wWlf[id] = pack2(s[0], s[1]);
    } else if ((id -= N2) < N3) {        // word bias sum [j][g]
      int g = id & 3, j = id>>2;
      wbsw[id] = bih_w[g*128+j] + bhh_w[g*128+j];
    } else if ((id -= N3) < N4) {        // sentence Whh in MFMA-B row layout [dir][ng][kp]
      int kp = id & 127, ng = (id>>7)&1023, dir = id>>17;
      int w = ng>>7, g = (ng>>5)&3, jl = ng&31;    // ng = wave*128 + g*32 + jl
      int row = g*256 + w*32 + jl;
      const float* s = (dir ? Whh_b : Whh_f) + (size_t)row*256 + 2*kp;
      wWs[id] = pack2(s[0], s[1]);
    } else if ((id -= N4) < N5) {        // sentence Wih packed [dir][kp][j][g], 306 = 153 pairs
      int dir = id >= 156672; int r = id - dir*156672;
      int g = r & 3, j = (r>>2)&255, kp = r>>10;
      const float* s = (dir ? Wih_b : Wih_f) + (size_t)(g*256+j)*306 + 2*kp;
      wWihs[id] = pack2(s[0], s[1]);
    } else if ((id -= N5) < N6) {        // sentence bias sums [dir][j][g]
      int g = id & 3, j = (id>>2)&255, dir = id>>10;
      int row = g*256+j;
      wbss[id] = dir ? (bih_b[row]+bhh_b[row]) : (bih_f[row]+bhh_f[row]);
    } else if ((id -= N6) < N7) {        // Wo packed [kp][o]
      int o = id & 31, kp = id>>5;
      const float* s = Wo + (size_t)o*512 + 2*kp;
      wWo[id] = pack2(s[0], s[1]);
    } else { id -= N7;                   // bert = Xw[:,20:198,0] -> sent[:,128:306]
      int wg = id / 178, ii = id % 178;
      sent[(size_t)wg*SROW + 128 + ii] = X[(size_t)wg*9900 + (20+ii)*50];
    }
  }
}

// ---- word LSTM via MFMA: 128 blocks x 16 words, 8 waves, N=512 (wave: 16 j x 4 gates).
// All weights in VGPRs (Whh 16 frags, Wih 8, Wl 4). Letters + h in static LDS.
__global__ __launch_bounds__(512, 2) void k_word(
    const float* __restrict__ X, const float* __restrict__ h0w, const float* __restrict__ c0w,
    const uint32_t* __restrict__ wWsw, const uint32_t* __restrict__ wWxw,
    const float* __restrict__ wbsw, const uint32_t* __restrict__ wWlf,
    const float* __restrict__ bl, float* __restrict__ sent)
{
  __shared__ __align__(16) uint32_t lets[11520];      // [t20][m16][36] f16x2 (72 cols, 50 real)
  __shared__ __align__(16) uint16_t hbuf[2][2176];    // [m16][136]
  const int tid = threadIdx.x;
  const int wave = tid >> 6, lane = tid & 63;
  const int l15 = lane & 15, l4 = lane >> 4;
  const int wg0 = blockIdx.x * 16;

  // B fragments (gate-grouped: ng = wave*64 + g*16 + jl)
  uint4 Bh[4][4], Bx[4][2];
  #pragma unroll
  for (int g = 0; g < 4; ++g) {
    int ng = wave*64 + g*16 + l15;
    #pragma unroll
    for (int Kt = 0; Kt < 4; ++Kt) Bh[g][Kt] = *(const uint4*)(wWsw + ng*64 + Kt*16 + l4*4);
    #pragma unroll
    for (int Kt = 0; Kt < 2; ++Kt) Bx[g][Kt] = *(const uint4*)(wWxw + ng*32 + Kt*16 + l4*4);
  }
  // stage letters (f16, zero-padded cols 50..71)
  for (int i = tid; i < 11520; i += 512) {
    int c = i % 36, mt = i / 36; int m = mt & 15, t = mt >> 4;
    lets[i] = (c < 25) ? pack2(X[(size_t)(wg0+m)*9900 + t*50 + 2*c],
                               X[(size_t)(wg0+m)*9900 + t*50 + 2*c + 1]) : 0u;
  }
  // h0
  for (int i = tid; i < 2048; i += 512) {
    int m = i >> 7, k = i & 127;
    hbuf[0][m*136 + k] = f16b(h0w[(size_t)(wg0+m)*128 + k]);
  }
  const float4 bs = *(const float4*)(wbsw + (wave*16 + l15)*4);
  float cr[4];
  #pragma unroll
  for (int r = 0; r < 4; ++r) cr[r] = c0w[(size_t)(wg0 + l4*4 + r)*128 + wave*16 + l15];
  __syncthreads();

  uint16_t* hc = hbuf[0];
  uint16_t* hn = hbuf[1];
  const uint16_t* lp = (const uint16_t*)lets;
  #pragma unroll 1
  for (int t = 0; t < 20; ++t) {
    f32x4_t acc[4];
    acc[0] = (f32x4_t){bs.x,bs.x,bs.x,bs.x};
    acc[1] = (f32x4_t){bs.y,bs.y,bs.y,bs.y};
    acc[2] = (f32x4_t){bs.z,bs.z,bs.z,bs.z};
    acc[3] = (f32x4_t){bs.w,bs.w,bs.w,bs.w};
    #pragma unroll
    for (int Kt = 0; Kt < 2; ++Kt) {          // xg: letters . Wih
      uint4 av = *(const uint4*)(lp + (t*16 + l15)*72 + Kt*32 + l4*8);
      half8_t a = __builtin_bit_cast(half8_t, av);
      #pragma unroll
      for (int g = 0; g < 4; ++g)
        acc[g] = __builtin_amdgcn_mfma_f32_16x16x32_f16(a, __builtin_bit_cast(half8_t, Bx[g][Kt]), acc[g], 0,0,0);
    }
    #pragma unroll
    for (int Kt = 0; Kt < 4; ++Kt) {          // recurrent: h . Whh
      uint4 av = *(const uint4*)(hc + l15*136 + Kt*32 + l4*8);
      half8_t a = __builtin_bit_cast(half8_t, av);
      #pragma unroll
      for (int g = 0; g < 4; ++g)
        acc[g] = __builtin_amdgcn_mfma_f32_16x16x32_f16(a, __builtin_bit_cast(half8_t, Bh[g][Kt]), acc[g], 0,0,0);
    }
    #pragma unroll
    for (int r = 0; r < 4; ++r) {             // gate order i,f,g,o
      float cc = sigm(acc[1][r])*cr[r] + sigm(acc[0][r])*tanhf_(acc[2][r]);
      cr[r] = cc;
      float hh = sigm(acc[3][r])*tanhf_(cc);
      hn[(l4*4+r)*136 + wave*16 + l15] = f16b(hh);
    }
    uint16_t* tp = hc; hc = hn; hn = tp;
    __syncthreads();
  }
  // word_rep = h_19 @ Wl^T + bl -> sent[:,0:128]
  uint4 Bl[4];
  #pragma unroll
  for (int Kt = 0; Kt < 4; ++Kt) Bl[Kt] = *(const uint4*)(wWlf + (wave*16 + l15)*64 + Kt*16 + l4*4);
  f32x4_t a2 = (f32x4_t){0.f,0.f,0.f,0.f};
  #pragma unroll
  for (int Kt = 0; Kt < 4; ++Kt) {
    uint4 av = *(const uint4*)(hc + l15*136 + Kt*32 + l4*8);
    a2 = __builtin_amdgcn_mfma_f32_16x16x32_f16(__builtin_bit_cast(half8_t, av),
                                                __builtin_bit_cast(half8_t, Bl[Kt]), a2, 0,0,0);
  }
  const float blv = bl[wave*16 + l15];
  #pragma unroll
  for (int r = 0; r < 4; ++r)
    sent[(size_t)(wg0 + l4*4 + r)*SROW + wave*16 + l15] = a2[r] + blv;
}

// ---- sentence xg GEMM -> xgq in srec per-pass-contiguous layout:
// idx(uint2) = ((((dir*64+tt)*2+half)*8+w)*2+jh)*256 + l15*16 + l4*4 + r
__global__ __launch_bounds__(256) void k_sxg(
    const float* __restrict__ sent, const uint32_t* __restrict__ Wihs,
    const float* __restrict__ bss, uint2* __restrict__ xgq)
{
  __shared__ uint32_t x16[153*8];
  const int tid = threadIdx.x;
  const int dir = blockIdx.x >> 8, rg = blockIdx.x & 255;
  for (int i = tid; i < 153*8; i += 256) {
    int r = i & 7, kp = i >> 3;
    int ot = rg*8 + r; int b = ot >> 6, tt = ot & 63;
    int si = dir ? (63 - tt) : tt;
    const float* s = sent + (size_t)(b*64 + si)*SROW + 2*kp;
    x16[kp*8 + r] = pack2(s[0], s[1]);
  }
  __syncthreads();
  const int j = tid;
  float acc[8][4];
  {
    const float4 b4 = *(const float4*)(bss + (dir*256 + j)*4);
    #pragma unroll
    for (int r = 0; r < 8; ++r) { acc[r][0]=b4.x; acc[r][1]=b4.y; acc[r][2]=b4.z; acc[r][3]=b4.w; }
  }
  for (int kp = 0; kp < 153; ++kp) {
    uint4 wv = *(const uint4*)(Wihs + ((size_t)(dir*153 + kp)*256 + j)*4);
    uint4 xa = *(const uint4*)(x16 + kp*8);
    uint4 xb = *(const uint4*)(x16 + kp*8 + 4);
    uint32_t wa[4] = {wv.x,wv.y,wv.z,wv.w};
    uint32_t xs[8] = {xa.x,xa.y,xa.z,xa.w,xb.x,xb.y,xb.z,xb.w};
    #pragma unroll
    for (int r = 0; r < 8; ++r)
      #pragma unroll
      for (int g = 0; g < 4; ++g) acc[r][g] = fdot2(wa[g], xs[r], acc[r][g]);
  }
  const int w = j >> 5, jh2 = (j >> 4) & 1, l15j = j & 15;
  #pragma unroll
  for (int r = 0; r < 8; ++r) {
    int ot = rg*8 + r; int b = ot >> 6, tt = ot & 63;
    int half = b >> 4, l4m = (b >> 2) & 3, rm = b & 3;
    uint2 v; v.x = pack2(acc[r][0], acc[r][1]); v.y = pack2(acc[r][2], acc[r][3]);
    size_t idx = ((((size_t)(dir*64 + tt)*2 + half)*8 + w)*2 + jh2)*256 + l15j*16 + l4m*4 + rm;
    xgq[idx] = v;
  }
}

// ---- sentence recurrence: grid 4 = (dir, batch-half M=16). 8 waves, N=1024.
// Breg[8][6]=192 VGPR + Kt{6,7} in LDS. Per-pass xg (8 regs), unroll-1 t-loop,
// sched_barrier phase fences, h dbuf + one raw barrier per step.
__global__ __launch_bounds__(512, 2) void k_srec(
    const uint32_t* __restrict__ Ws, const float* __restrict__ h0f, const float* __restrict__ c0f,
    const float* __restrict__ h0b, const float* __restrict__ c0b,
    const uint2* __restrict__ xgq, uint16_t* __restrict__ outfb)
{
  extern __shared__ char smem[];               // [0,131072) B-frags, then h dbuf 2x[16][264]
  uint16_t* h16a = (uint16_t*)(smem + 131072);
  uint16_t* h16b = h16a + 4224;
  const int tid = threadIdx.x;
  const int wave = tid >> 6, lane = tid & 63;
  const int dir = blockIdx.x >> 1, half = blockIdx.x & 1, m0 = half * 16;
  const int l15 = lane & 15, l4 = lane >> 4;

  uint4 Breg[8][6];
  #pragma unroll
  for (int Nt = 0; Nt < 8; ++Nt) {
    #pragma unroll
    for (int Kt = 0; Kt < 8; ++Kt) {
      int ng = wave*128 + Nt*16 + l15;
      int kq = Kt*16 + l4*4;                   // u32 index = k0/2
      uint4 v = *(const uint4*)(Ws + (size_t)(dir*1024 + ng)*128 + kq);
      if (Kt < 6) Breg[Nt][Kt] = v;
      else *(uint4*)(smem + (((wave*16 + Nt*2 + (Kt-6))*64 + lane)*16)) = v;
    }
  }
  {
    const float* h0 = dir ? h0b : h0f;
    for (int i = tid; i < 16*256; i += 512) {
      int m = i >> 8, k = i & 255;
      h16a[m*264 + k] = f16b(h0[(size_t)(m0+m)*256 + k]);
    }
  }
  float cr[2][4];
  {
    const float* c0 = dir ? c0b : c0f;
    #pragma unroll
    for (int jh = 0; jh < 2; ++jh)
      #pragma unroll
      for (int r = 0; r < 4; ++r) {
        int m = l4*4 + r, jj = wave*32 + jh*16 + l15;
        cr[jh][r] = c0[(size_t)(m0+m)*256 + jj];
      }
  }
  __syncthreads();

  const char* xb = (const char*)xgq + ((size_t)dir*524288 + (size_t)half*4096)*8;
  const int xoff = wave*4096 + l15*128 + l4*32;
  const int s0 = dir ? 63 : 0, dstep = dir ? -1 : 1;
  uint16_t* op = outfb + ((size_t)(m0 + l4*4)*64 + s0)*512 + dir*256 + wave*32 + l15;

  uint16_t* hc = h16a;
  uint16_t* hn = h16b;
  #pragma unroll 1
  for (int t = 0; t < 64; ++t) {
    #pragma unroll
    for (int jh = 0; jh < 2; ++jh) {                 // gate-half pass: Nt = g*2+jh
      const char* xbl = xb + (xoff + jh*2048);
      uint4 xga = *(const uint4*)(xbl);
      uint4 xgb = *(const uint4*)(xbl + 16);
      f32x4_t acc[4];
      #pragma unroll
      for (int g = 0; g < 4; ++g) acc[g] = (f32x4_t){0.f,0.f,0.f,0.f};
      #pragma unroll
      for (int Kt = 0; Kt < 8; ++Kt) {
        uint4 av = *(const uint4*)(hc + l15*264 + Kt*32 + l4*8);
        half8_t a = __builtin_bit_cast(half8_t, av);
        #pragma unroll
        for (int g = 0; g < 4; ++g) {
          const int Nt = g*2 + jh;
          uint4 bv = (Kt < 6) ? Breg[Nt][Kt]
                   : *(const uint4*)(smem + (((wave*16 + Nt*2 + (Kt-6))*64 + lane)*16));
          acc[g] = __builtin_amdgcn_mfma_f32_16x16x32_f16(a, __builtin_bit_cast(half8_t, bv), acc[g], 0,0,0);
        }
      }
      #pragma unroll
      for (int r = 0; r < 4; ++r) {
        uint32_t ux = (r==0) ? xga.x : (r==1) ? xga.z : (r==2) ? xgb.x : xgb.z;
        uint32_t uy = (r==0) ? xga.y : (r==1) ? xga.w : (r==2) ? xgb.y : xgb.w;
        float gi = acc[0][r] + lo16(ux);
        float gf = acc[1][r] + hi16(ux);
        float gg = acc[2][r] + lo16(uy);
        float go = acc[3][r] + hi16(uy);
        // fused-denominator LSTM update: 5 exp + 2 rcp
        float ef = __expf(-gf), ei = __expf(-gi), eg = __expf(-2.f*gg);
        float pef = 1.f + ef, pei = 1.f + ei, peg = 1.f + eg;
        float num = cr[jh][r]*pei*peg + (1.f - eg)*pef;
        float cc  = num * __builtin_amdgcn_rcpf(pef*pei*peg);
        cr[jh][r] = cc;
        float ec = __expf(-2.f*cc), eo = __expf(-go);
        float hh = (1.f - ec) * __builtin_amdgcn_rcpf((1.f + ec)*(1.f + eo));
        uint16_t hb = f16b(hh);
        hn[(l4*4+r)*264 + wave*32 + jh*16 + l15] = hb;
        op[(size_t)r*32768 + jh*16] = hb;
      }
      __builtin_amdgcn_sched_barrier(0);
    }
    { uint16_t* tp = hc; hc = hn; hn = tp; }
    xb += 65536;
    op += dstep * 512;
    // h dbuf: only this step's LDS writes must be visible; stores/loads fly across
    asm volatile("s_waitcnt lgkmcnt(0)\ns_barrier" ::: "memory");
    __builtin_amdgcn_sched_barrier(0);
  }
}

// ---- tags + softmax
__global__ __launch_bounds__(256) void k_tags(
    const uint16_t* __restrict__ outfb, const uint32_t* __restrict__ Wo16,
    const float* __restrict__ bo, float* __restrict__ out)
{
  __shared__ uint32_t xr[8*256];
  const int tid = threadIdx.x;
  const int w0 = blockIdx.x * 8;
  const uint32_t* src = (const uint32_t*)outfb;
  for (int i = tid; i < 2048; i += 256) {
    int w = i >> 8, kp = i & 255;
    xr[i] = src[(size_t)(w0+w)*256 + kp];
  }
  __syncthreads();
  const int o = tid & 31, w = tid >> 5;
  float a = bo[o];
  for (int kp = 0; kp < 256; ++kp)
    a = fdot2(Wo16[kp*32 + o], xr[w*256 + kp], a);
  float mx = a;
  #pragma unroll
  for (int off = 16; off; off >>= 1) mx = fmaxf(mx, __shfl_xor(mx, off, 32));
  float e = __expf(a - mx);
  float ssum = e;
  #pragma unroll
  for (int off = 16; off; off >>= 1) ssum += __shfl_xor(ssum, off, 32);
  out[(size_t)(w0+w)*32 + o] = e * __builtin_amdgcn_rcpf(ssum);
}

extern "C" void kernel_launch(void* const* d_in, const int* in_sizes, int n_in,
                              void* d_out, int out_size, void* d_ws, size_t ws_size,
                              hipStream_t stream) {
  const float* X     = (const float*)d_in[0];
  const float* h0w   = (const float*)d_in[1];
  const float* c0w   = (const float*)d_in[2];
  const float* h0f   = (const float*)d_in[3];
  const float* c0f   = (const float*)d_in[4];
  const float* h0b   = (const float*)d_in[5];
  const float* c0b   = (const float*)d_in[6];
  const float* Wih_w = (const float*)d_in[7];
  const float* Whh_w = (const float*)d_in[8];
  const float* bih_w = (const float*)d_in[9];
  const float* bhh_w = (const float*)d_in[10];
  const float* Wl    = (const float*)d_in[11];
  const float* bl    = (const float*)d_in[12];
  const float* Wih_f = (const float*)d_in[13];
  const float* Whh_f = (const float*)d_in[14];
  const float* bih_f = (const float*)d_in[15];
  const float* bhh_f = (const float*)d_in[16];
  const float* Wih_b = (const float*)d_in[17];
  const float* Whh_b = (const float*)d_in[18];
  const float* bih_b = (const float*)d_in[19];
  const float* bhh_b = (const float*)d_in[20];
  const float* Wo    = (const float*)d_in[21];
  const float* bo    = (const float*)d_in[22];

  char* ws = (char*)d_ws;
  uint32_t* wWsw  = (uint32_t*)(ws + 0);          // 131072 B
  uint32_t* wWxw  = (uint32_t*)(ws + 131072);     // 65536 B
  uint32_t* wWlf  = (uint32_t*)(ws + 196608);     // 32768 B
  float*    wbsw  = (float*)   (ws + 229376);     // 2048 B
  uint32_t* wWs   = (uint32_t*)(ws + 231424);     // 1048576 B
  uint32_t* wWihs = (uint32_t*)(ws + 1280000);    // 1253376 B
  float*    wbss  = (float*)   (ws + 2533376);    // 8192 B
  uint32_t* wWo   = (uint32_t*)(ws + 2541568);    // 32768 B
  float*    sent  = (float*)   (ws + 2574336);    // 2523136 B
  uint2*    xgq   = (uint2*)   (ws + 5097472);    // 8388608 B
  uint16_t* outfb = (uint16_t*)(ws + 13486080);   // 2097152 B -> end ~15.6 MB

  hipFuncSetAttribute((const void*)k_srec, hipFuncAttributeMaxDynamicSharedMemorySize, 147968);

  k_prep<<<2048, 256, 0, stream>>>(X, Wih_w, Whh_w, bih_w, bhh_w, Wl, Wih_f, Whh_f, bih_f, bhh_f,
                                   Wih_b, Whh_b, bih_b, bhh_b, Wo,
                                   wWsw, wWxw, wWlf, wbsw, wWs, wWihs, wbss, wWo, sent);
  k_word<<<128, 512, 0, stream>>>(X, h0w, c0w, wWsw, wWxw, wbsw, wWlf, bl, sent);
  k_sxg<<<512, 256, 0, stream>>>(sent, wWihs, wbss, xgq);
  k_srec<<<4, 512, 147968, stream>>>(wWs, h0f, c0f, h0b, c0b, xgq, outfb);
  k_tags<<<256, 256, 0, stream>>>(outfb, wWo, bo, (float*)d_out);
}

// Round 4
// 308.346 us; speedup vs baseline: 1.8737x; 1.0898x over previous
//
#include <hip/hip_runtime.h>
#include <cstdint>
#include <cstddef>

#define DI static __device__ __forceinline__

using half_t  = _Float16;
using half2_t = __attribute__((ext_vector_type(2))) _Float16;
using half8_t = __attribute__((ext_vector_type(8))) _Float16;
using f32x4_t = __attribute__((ext_vector_type(4))) float;

DI uint32_t pack2(float a, float b){ half2_t h; h[0]=(half_t)a; h[1]=(half_t)b; return __builtin_bit_cast(uint32_t,h); }
DI uint16_t f16b(float a){ return __builtin_bit_cast(uint16_t,(half_t)a); }
DI float lo16(uint32_t u){ half2_t h=__builtin_bit_cast(half2_t,u); return (float)h[0]; }
DI float hi16(uint32_t u){ half2_t h=__builtin_bit_cast(half2_t,u); return (float)h[1]; }
DI float fdot2(uint32_t w, uint32_t x, float acc){
  return __builtin_amdgcn_fdot2(__builtin_bit_cast(half2_t,w), __builtin_bit_cast(half2_t,x), acc, false);
}
DI float sigm(float x){ return __builtin_amdgcn_rcpf(1.f + __expf(-x)); }
DI float tanhf_(float x){ return 1.f - 2.f*__builtin_amdgcn_rcpf(__expf(2.f*x)+1.f); }

// problem sizes: B=32 S=64 NW=2048 T=198 L=50 WLEN=20 BERT=178 Hs=128 Hm=256 Din=306 O=32
#define SROW 308   // sentences_in row stride (306 used)
#define HSTR 280   // k_srec h-row stride in halves (560 B = 140 dw ≡ 12 mod 32: free 2-way banks)

// prep job sizes
#define N0 32768   // word Whh MFMA-B frags [ng512][kp64]
#define N1 16384   // word Wih MFMA-B frags [ng512][kp32] (k=50 zero-padded to 64)
#define N2 8192    // Wl MFMA-B frags [d128][kp64]
#define N3 512     // word bias sum [j128][g4]
#define N4 262144  // sent Whh B-frag layout [dir][ng1024][kp128]
#define N5 313344  // sent Wih f16x2 [dir][kp153][j256][g4]
#define N6 2048    // sent bias sum [dir][j256][g4]
#define N7 8192    // Wo f16x2 [kp256][o32]
#define N8 364544  // bert -> sent[:,128:306]
#define NTOT (N0+N1+N2+N3+N4+N5+N6+N7+N8)

__global__ void k_prep(const float* __restrict__ X,
                       const float* __restrict__ Wih_w, const float* __restrict__ Whh_w,
                       const float* __restrict__ bih_w, const float* __restrict__ bhh_w,
                       const float* __restrict__ Wl,
                       const float* __restrict__ Wih_f, const float* __restrict__ Whh_f,
                       const float* __restrict__ bih_f, const float* __restrict__ bhh_f,
                       const float* __restrict__ Wih_b, const float* __restrict__ Whh_b,
                       const float* __restrict__ bih_b, const float* __restrict__ bhh_b,
                       const float* __restrict__ Wo,
                       uint32_t* __restrict__ wWsw, uint32_t* __restrict__ wWxw,
                       uint32_t* __restrict__ wWlf, float* __restrict__ wbsw,
                       uint32_t* __restrict__ wWs, uint32_t* __restrict__ wWihs,
                       float* __restrict__ wbss, uint32_t* __restrict__ wWo,
                       float* __restrict__ sent)
{
  for (int i = blockIdx.x*blockDim.x + threadIdx.x; i < NTOT; i += gridDim.x*blockDim.x) {
    int id = i;
    if (id < N0) {                       // word Whh B-frags: ng = w*64+g*16+jl -> row g*128+w*16+jl
      int kp = id & 63, ng = id >> 6;
      int w = ng>>6, g = (ng>>4)&3, jl = ng&15;
      const float* s = Whh_w + (size_t)(g*128 + w*16 + jl)*128 + 2*kp;
      wWsw[id] = pack2(s[0], s[1]);
    } else if ((id -= N0) < N1) {        // word Wih B-frags, k padded 50->64
      int kp = id & 31, ng = id >> 5;
      int w = ng>>6, g = (ng>>4)&3, jl = ng&15;
      if (kp < 25) {
        const float* s = Wih_w + (size_t)(g*128 + w*16 + jl)*50 + 2*kp;
        wWxw[id] = pack2(s[0], s[1]);
      } else wWxw[id] = 0u;
    } else if ((id -= N1) < N2) {        // Wl B-frags [d][kp]
      int kp = id & 63, d = id >> 6;
      const float* s = Wl + (size_t)d*128 + 2*kp;
      wWlf[id] = pack2(s[0], s[1]);
    } else if ((id -= N2) < N3) {        // word bias sum [j][g]
      int g = id & 3, j = id>>2;
      wbsw[id] = bih_w[g*128+j] + bhh_w[g*128+j];
    } else if ((id -= N3) < N4) {        // sentence Whh in MFMA-B row layout [dir][ng][kp]
      int kp = id & 127, ng = (id>>7)&1023, dir = id>>17;
      int w = ng>>7, g = (ng>>5)&3, jl = ng&31;    // ng = wave*128 + g*32 + jl
      int row = g*256 + w*32 + jl;
      const float* s = (dir ? Whh_b : Whh_f) + (size_t)row*256 + 2*kp;
      wWs[id] = pack2(s[0], s[1]);
    } else if ((id -= N4) < N5) {        // sentence Wih packed [dir][kp][j][g], 306 = 153 pairs
      int dir = id >= 156672; int r = id - dir*156672;
      int g = r & 3, j = (r>>2)&255, kp = r>>10;
      const float* s = (dir ? Wih_b : Wih_f) + (size_t)(g*256+j)*306 + 2*kp;
      wWihs[id] = pack2(s[0], s[1]);
    } else if ((id -= N5) < N6) {        // sentence bias sums [dir][j][g]
      int g = id & 3, j = (id>>2)&255, dir = id>>10;
      int row = g*256+j;
      wbss[id] = dir ? (bih_b[row]+bhh_b[row]) : (bih_f[row]+bhh_f[row]);
    } else if ((id -= N6) < N7) {        // Wo packed [kp][o]
      int o = id & 31, kp = id>>5;
      const float* s = Wo + (size_t)o*512 + 2*kp;
      wWo[id] = pack2(s[0], s[1]);
    } else { id -= N7;                   // bert = Xw[:,20:198,0] -> sent[:,128:306]
      int wg = id / 178, ii = id % 178;
      sent[(size_t)wg*SROW + 128 + ii] = X[(size_t)wg*9900 + (20+ii)*50];
    }
  }
}

// ---- word LSTM via MFMA: 128 blocks x 16 words, 8 waves, N=512 (wave: 16 j x 4 gates).
// All weights in VGPRs (Whh 16 frags, Wih 8, Wl 4). Letters + h in static LDS.
__global__ __launch_bounds__(512, 2) void k_word(
    const float* __restrict__ X, const float* __restrict__ h0w, const float* __restrict__ c0w,
    const uint32_t* __restrict__ wWsw, const uint32_t* __restrict__ wWxw,
    const float* __restrict__ wbsw, const uint32_t* __restrict__ wWlf,
    const float* __restrict__ bl, float* __restrict__ sent)
{
  __shared__ __align__(16) uint32_t lets[11520];      // [t20][m16][36] f16x2 (72 cols, 50 real)
  __shared__ __align__(16) uint16_t hbuf[2][2176];    // [m16][136]
  const int tid = threadIdx.x;
  const int wave = tid >> 6, lane = tid & 63;
  const int l15 = lane & 15, l4 = lane >> 4;
  const int wg0 = blockIdx.x * 16;

  // B fragments (gate-grouped: ng = wave*64 + g*16 + jl)
  uint4 Bh[4][4], Bx[4][2];
  #pragma unroll
  for (int g = 0; g < 4; ++g) {
    int ng = wave*64 + g*16 + l15;
    #pragma unroll
    for (int Kt = 0; Kt < 4; ++Kt) Bh[g][Kt] = *(const uint4*)(wWsw + ng*64 + Kt*16 + l4*4);
    #pragma unroll
    for (int Kt = 0; Kt < 2; ++Kt) Bx[g][Kt] = *(const uint4*)(wWxw + ng*32 + Kt*16 + l4*4);
  }
  // stage letters (f16, zero-padded cols 50..71)
  for (int i = tid; i < 11520; i += 512) {
    int c = i % 36, mt = i / 36; int m = mt & 15, t = mt >> 4;
    lets[i] = (c < 25) ? pack2(X[(size_t)(wg0+m)*9900 + t*50 + 2*c],
                               X[(size_t)(wg0+m)*9900 + t*50 + 2*c + 1]) : 0u;
  }
  // h0
  for (int i = tid; i < 2048; i += 512) {
    int m = i >> 7, k = i & 127;
    hbuf[0][m*136 + k] = f16b(h0w[(size_t)(wg0+m)*128 + k]);
  }
  const float4 bs = *(const float4*)(wbsw + (wave*16 + l15)*4);
  float cr[4];
  #pragma unroll
  for (int r = 0; r < 4; ++r) cr[r] = c0w[(size_t)(wg0 + l4*4 + r)*128 + wave*16 + l15];
  __syncthreads();

  uint16_t* hc = hbuf[0];
  uint16_t* hn = hbuf[1];
  const uint16_t* lp = (const uint16_t*)lets;
  #pragma unroll 1
  for (int t = 0; t < 20; ++t) {
    f32x4_t acc[4];
    acc[0] = (f32x4_t){bs.x,bs.x,bs.x,bs.x};
    acc[1] = (f32x4_t){bs.y,bs.y,bs.y,bs.y};
    acc[2] = (f32x4_t){bs.z,bs.z,bs.z,bs.z};
    acc[3] = (f32x4_t){bs.w,bs.w,bs.w,bs.w};
    #pragma unroll
    for (int Kt = 0; Kt < 2; ++Kt) {          // xg: letters . Wih
      uint4 av = *(const uint4*)(lp + (t*16 + l15)*72 + Kt*32 + l4*8);
      half8_t a = __builtin_bit_cast(half8_t, av);
      #pragma unroll
      for (int g = 0; g < 4; ++g)
        acc[g] = __builtin_amdgcn_mfma_f32_16x16x32_f16(a, __builtin_bit_cast(half8_t, Bx[g][Kt]), acc[g], 0,0,0);
    }
    #pragma unroll
    for (int Kt = 0; Kt < 4; ++Kt) {          // recurrent: h . Whh
      uint4 av = *(const uint4*)(hc + l15*136 + Kt*32 + l4*8);
      half8_t a = __builtin_bit_cast(half8_t, av);
      #pragma unroll
      for (int g = 0; g < 4; ++g)
        acc[g] = __builtin_amdgcn_mfma_f32_16x16x32_f16(a, __builtin_bit_cast(half8_t, Bh[g][Kt]), acc[g], 0,0,0);
    }
    #pragma unroll
    for (int r = 0; r < 4; ++r) {             // gate order i,f,g,o
      float cc = sigm(acc[1][r])*cr[r] + sigm(acc[0][r])*tanhf_(acc[2][r]);
      cr[r] = cc;
      float hh = sigm(acc[3][r])*tanhf_(cc);
      hn[(l4*4+r)*136 + wave*16 + l15] = f16b(hh);
    }
    uint16_t* tp = hc; hc = hn; hn = tp;
    __syncthreads();
  }
  // word_rep = h_19 @ Wl^T + bl -> sent[:,0:128]
  uint4 Bl[4];
  #pragma unroll
  for (int Kt = 0; Kt < 4; ++Kt) Bl[Kt] = *(const uint4*)(wWlf + (wave*16 + l15)*64 + Kt*16 + l4*4);
  f32x4_t a2 = (f32x4_t){0.f,0.f,0.f,0.f};
  #pragma unroll
  for (int Kt = 0; Kt < 4; ++Kt) {
    uint4 av = *(const uint4*)(hc + l15*136 + Kt*32 + l4*8);
    a2 = __builtin_amdgcn_mfma_f32_16x16x32_f16(__builtin_bit_cast(half8_t, av),
                                                __builtin_bit_cast(half8_t, Bl[Kt]), a2, 0,0,0);
  }
  const float blv = bl[wave*16 + l15];
  #pragma unroll
  for (int r = 0; r < 4; ++r)
    sent[(size_t)(wg0 + l4*4 + r)*SROW + wave*16 + l15] = a2[r] + blv;
}

// ---- sentence xg GEMM -> xgq in srec per-pass-contiguous layout:
// idx(uint2) = ((((dir*64+tt)*2+half)*8+w)*2+jh)*256 + l15*16 + l4*4 + r
__global__ __launch_bounds__(256) void k_sxg(
    const float* __restrict__ sent, const uint32_t* __restrict__ Wihs,
    const float* __restrict__ bss, uint2* __restrict__ xgq)
{
  __shared__ uint32_t x16[153*8];
  const int tid = threadIdx.x;
  const int dir = blockIdx.x >> 8, rg = blockIdx.x & 255;
  for (int i = tid; i < 153*8; i += 256) {
    int r = i & 7, kp = i >> 3;
    int ot = rg*8 + r; int b = ot >> 6, tt = ot & 63;
    int si = dir ? (63 - tt) : tt;
    const float* s = sent + (size_t)(b*64 + si)*SROW + 2*kp;
    x16[kp*8 + r] = pack2(s[0], s[1]);
  }
  __syncthreads();
  const int j = tid;
  float acc[8][4];
  {
    const float4 b4 = *(const float4*)(bss + (dir*256 + j)*4);
    #pragma unroll
    for (int r = 0; r < 8; ++r) { acc[r][0]=b4.x; acc[r][1]=b4.y; acc[r][2]=b4.z; acc[r][3]=b4.w; }
  }
  for (int kp = 0; kp < 153; ++kp) {
    uint4 wv = *(const uint4*)(Wihs + ((size_t)(dir*153 + kp)*256 + j)*4);
    uint4 xa = *(const uint4*)(x16 + kp*8);
    uint4 xb = *(const uint4*)(x16 + kp*8 + 4);
    uint32_t wa[4] = {wv.x,wv.y,wv.z,wv.w};
    uint32_t xs[8] = {xa.x,xa.y,xa.z,xa.w,xb.x,xb.y,xb.z,xb.w};
    #pragma unroll
    for (int r = 0; r < 8; ++r)
      #pragma unroll
      for (int g = 0; g < 4; ++g) acc[r][g] = fdot2(wa[g], xs[r], acc[r][g]);
  }
  const int w = j >> 5, jh2 = (j >> 4) & 1, l15j = j & 15;
  #pragma unroll
  for (int r = 0; r < 8; ++r) {
    int ot = rg*8 + r; int b = ot >> 6, tt = ot & 63;
    int half = b >> 4, l4m = (b >> 2) & 3, rm = b & 3;
    uint2 v; v.x = pack2(acc[r][0], acc[r][1]); v.y = pack2(acc[r][2], acc[r][3]);
    size_t idx = ((((size_t)(dir*64 + tt)*2 + half)*8 + w)*2 + jh2)*256 + l15j*16 + l4m*4 + rm;
    xgq[idx] = v;
  }
}

// ---- sentence recurrence: grid 4 = (dir, batch-half M=16). 8 waves, N=1024.
// HARD reg budget (512 thr => 2 waves/SIMD => 256 unified regs/wave):
// Breg[8][6]=192, acc 16, cr 8, transient xg, imm-offset stores, no fences.
// outfb layout (halves): ((((s*2+half)*2+dir)*16+m)*8+wave)*32 + jh*16 + l15
__global__ __launch_bounds__(512, 2) void k_srec(
    const uint32_t* __restrict__ Ws, const float* __restrict__ h0f, const float* __restrict__ c0f,
    const float* __restrict__ h0b, const float* __restrict__ c0b,
    const uint2* __restrict__ xgq, uint16_t* __restrict__ outfb)
{
  extern __shared__ char smem[];               // [0,131072) B-frags, then h dbuf 2x[16][HSTR]
  uint16_t* h16a = (uint16_t*)(smem + 131072);
  uint16_t* h16b = h16a + 16*HSTR;
  const int tid = threadIdx.x;
  const int wave = tid >> 6, lane = tid & 63;
  const int dir = blockIdx.x >> 1, half = blockIdx.x & 1, m0 = half * 16;
  const int l15 = lane & 15, l4 = lane >> 4;

  uint4 Breg[8][6];
  #pragma unroll
  for (int Nt = 0; Nt < 8; ++Nt) {
    #pragma unroll
    for (int Kt = 0; Kt < 8; ++Kt) {
      int ng = wave*128 + Nt*16 + l15;
      int kq = Kt*16 + l4*4;                   // u32 index = k0/2
      uint4 v = *(const uint4*)(Ws + (size_t)(dir*1024 + ng)*128 + kq);
      if (Kt < 6) Breg[Nt][Kt] = v;
      else *(uint4*)(smem + (((wave*16 + Nt*2 + (Kt-6))*64 + lane)*16)) = v;
    }
  }
  {
    const float* h0 = dir ? h0b : h0f;
    for (int i = tid; i < 16*256; i += 512) {
      int m = i >> 8, k = i & 255;
      h16a[m*HSTR + k] = f16b(h0[(size_t)(m0+m)*256 + k]);
    }
  }
  float cr[2][4];
  {
    const float* c0 = dir ? c0b : c0f;
    #pragma unroll
    for (int jh = 0; jh < 2; ++jh)
      #pragma unroll
      for (int r = 0; r < 4; ++r) {
        int m = l4*4 + r, jj = wave*32 + jh*16 + l15;
        cr[jh][r] = c0[(size_t)(m0+m)*256 + jj];
      }
  }
  __syncthreads();

  // xg per-lane byte offset (jh handled by +2048 imm-able addressing below)
  const char* xb = (const char*)xgq + ((size_t)dir*4194304 + (size_t)half*32768)
                 + wave*4096 + l15*128 + l4*32;
  // outfb per-lane base (bytes): s*65536 + half*32768 + dir*16384 + m*512 + wave*64 + l15*2
  const int s0 = dir ? 63 : 0;
  const int sdelta = dir ? -65536 : 65536;
  char* op = (char*)outfb + (size_t)s0*65536 + half*32768 + dir*16384
           + (l4*4)*512 + wave*64 + l15*2;

  uint16_t* hc = h16a;
  uint16_t* hn = h16b;
  #pragma unroll 1
  for (int t = 0; t < 64; ++t) {
    // both passes' xg loads issued up front (latency hidden under pass 0 MFMAs)
    uint4 xg0a = *(const uint4*)(xb);
    uint4 xg0b = *(const uint4*)(xb + 16);
    uint4 xg1a = *(const uint4*)(xb + 2048);
    uint4 xg1b = *(const uint4*)(xb + 2048 + 16);

    #pragma unroll
    for (int jh = 0; jh < 2; ++jh) {                 // gate-half pass: Nt = g*2+jh
      const uint4 xga = jh ? xg1a : xg0a;
      const uint4 xgb = jh ? xg1b : xg0b;
      f32x4_t acc[4];                                // acc[g][r], seeded with xg preacts
      acc[0] = (f32x4_t){lo16(xga.x), lo16(xga.z), lo16(xgb.x), lo16(xgb.z)};  // i
      acc[1] = (f32x4_t){hi16(xga.x), hi16(xga.z), hi16(xgb.x), hi16(xgb.z)};  // f
      acc[2] = (f32x4_t){lo16(xga.y), lo16(xga.w), lo16(xgb.y), lo16(xgb.w)};  // g
      acc[3] = (f32x4_t){hi16(xga.y), hi16(xga.w), hi16(xgb.y), hi16(xgb.w)};  // o
      #pragma unroll
      for (int Kt = 0; Kt < 8; ++Kt) {
        uint4 av = *(const uint4*)(hc + l15*HSTR + Kt*32 + l4*8);
        half8_t a = __builtin_bit_cast(half8_t, av);
        #pragma unroll
        for (int g = 0; g < 4; ++g) {
          const int Nt = g*2 + jh;
          uint4 bv = (Kt < 6) ? Breg[Nt][Kt]
                   : *(const uint4*)(smem + (((wave*16 + Nt*2 + (Kt-6))*64 + lane)*16));
          acc[g] = __builtin_amdgcn_mfma_f32_16x16x32_f16(a, __builtin_bit_cast(half8_t, bv), acc[g], 0,0,0);
        }
      }
      #pragma unroll
      for (int r = 0; r < 4; ++r) {
        float gi = acc[0][r], gf = acc[1][r], gg = acc[2][r], go = acc[3][r];
        // fused-denominator LSTM update: 5 exp + 2 rcp
        float ef = __expf(-gf), ei = __expf(-gi), eg = __expf(-2.f*gg);
        float pef = 1.f + ef, pei = 1.f + ei, peg = 1.f + eg;
        float num = cr[jh][r]*pei*peg + (1.f - eg)*pef;
        float cc  = num * __builtin_amdgcn_rcpf(pef*pei*peg);
        cr[jh][r] = cc;
        float ec = __expf(-2.f*cc), eo = __expf(-go);
        float hh = (1.f - ec) * __builtin_amdgcn_rcpf((1.f + ec)*(1.f + eo));
        uint16_t hb = f16b(hh);
        hn[(l4*4+r)*HSTR + wave*32 + jh*16 + l15] = hb;
        *(uint16_t*)(op + r*512 + jh*32) = hb;       // imm-offset store (max 1568 B)
      }
    }
    { uint16_t* tp = hc; hc = hn; hn = tp; }
    xb += 65536;
    op += sdelta;
    // h dbuf: only this step's LDS ops must drain; global loads/stores fly across
    asm volatile("s_waitcnt lgkmcnt(0)\ns_barrier" ::: "memory");
  }
}

// ---- tags + softmax (reads the srec outfb layout)
__global__ __launch_bounds__(256) void k_tags(
    const uint16_t* __restrict__ outfb, const uint32_t* __restrict__ Wo16,
    const float* __restrict__ bo, float* __restrict__ out)
{
  __shared__ uint32_t xr[8*256];
  const int tid = threadIdx.x;
  const int w0 = blockIdx.x * 8;
  const uint32_t* src = (const uint32_t*)outfb;
  for (int i = tid; i < 2048; i += 256) {
    int w = i >> 8, kp = i & 255;                // kp: u32 over k = dir*256 + wave*32 + jh*16 + l15
    int widx = w0 + w;
    int s = widx & 63, q = widx >> 6;
    int half = q >> 4, m = q & 15;
    int dir = kp >> 7, wv = (kp >> 4) & 7, jh = (kp >> 3) & 1, l15h = kp & 7;
    xr[i] = src[s*16384 + half*8192 + dir*4096 + m*128 + wv*16 + jh*8 + l15h];
  }
  __syncthreads();
  const int o = tid & 31, w = tid >> 5;
  float a = bo[o];
  for (int kp = 0; kp < 256; ++kp)
    a = fdot2(Wo16[kp*32 + o], xr[w*256 + kp], a);
  float mx = a;
  #pragma unroll
  for (int off = 16; off; off >>= 1) mx = fmaxf(mx, __shfl_xor(mx, off, 32));
  float e = __expf(a - mx);
  float ssum = e;
  #pragma unroll
  for (int off = 16; off; off >>= 1) ssum += __shfl_xor(ssum, off, 32);
  out[(size_t)(w0+w)*32 + o] = e * __builtin_amdgcn_rcpf(ssum);
}

extern "C" void kernel_launch(void* const* d_in, const int* in_sizes, int n_in,
                              void* d_out, int out_size, void* d_ws, size_t ws_size,
                              hipStream_t stream) {
  const float* X     = (const float*)d_in[0];
  const float* h0w   = (const float*)d_in[1];
  const float* c0w   = (const float*)d_in[2];
  const float* h0f   = (const float*)d_in[3];
  const float* c0f   = (const float*)d_in[4];
  const float* h0b   = (const float*)d_in[5];
  const float* c0b   = (const float*)d_in[6];
  const float* Wih_w = (const float*)d_in[7];
  const float* Whh_w = (const float*)d_in[8];
  const float* bih_w = (const float*)d_in[9];
  const float* bhh_w = (const float*)d_in[10];
  const float* Wl    = (const float*)d_in[11];
  const float* bl    = (const float*)d_in[12];
  const float* Wih_f = (const float*)d_in[13];
  const float* Whh_f = (const float*)d_in[14];
  const float* bih_f = (const float*)d_in[15];
  const float* bhh_f = (const float*)d_in[16];
  const float* Wih_b = (const float*)d_in[17];
  const float* Whh_b = (const float*)d_in[18];
  const float* bih_b = (const float*)d_in[19];
  const float* bhh_b = (const float*)d_in[20];
  const float* Wo    = (const float*)d_in[21];
  const float* bo    = (const float*)d_in[22];

  char* ws = (char*)d_ws;
  uint32_t* wWsw  = (uint32_t*)(ws + 0);          // 131072 B
  uint32_t* wWxw  = (uint32_t*)(ws + 131072);     // 65536 B
  uint32_t* wWlf  = (uint32_t*)(ws + 196608);     // 32768 B
  float*    wbsw  = (float*)   (ws + 229376);     // 2048 B
  uint32_t* wWs   = (uint32_t*)(ws + 231424);     // 1048576 B
  uint32_t* wWihs = (uint32_t*)(ws + 1280000);    // 1253376 B
  float*    wbss  = (float*)   (ws + 2533376);    // 8192 B
  uint32_t* wWo   = (uint32_t*)(ws + 2541568);    // 32768 B
  float*    sent  = (float*)   (ws + 2574336);    // 2523136 B
  uint2*    xgq   = (uint2*)   (ws + 5097472);    // 8388608 B
  uint16_t* outfb = (uint16_t*)(ws + 13486080);   // 2097152 B -> end ~15.6 MB

  hipFuncSetAttribute((const void*)k_srec, hipFuncAttributeMaxDynamicSharedMemorySize, 148992);

  k_prep<<<2048, 256, 0, stream>>>(X, Wih_w, Whh_w, bih_w, bhh_w, Wl, Wih_f, Whh_f, bih_f, bhh_f,
                                   Wih_b, Whh_b, bih_b, bhh_b, Wo,
                                   wWsw, wWxw, wWlf, wbsw, wWs, wWihs, wbss, wWo, sent);
  k_word<<<128, 512, 0, stream>>>(X, h0w, c0w, wWsw, wWxw, wbsw, wWlf, bl, sent);
  k_sxg<<<512, 256, 0, stream>>>(sent, wWihs, wbss, xgq);
  k_srec<<<4, 512, 148992, stream>>>(wWs, h0f, c0f, h0b, c0b, xgq, outfb);
  k_tags<<<256, 256, 0, stream>>>(outfb, wWo, bo, (float*)d_out);
}